// Round 16
// baseline (99.656 us; speedup 1.0000x reference)
//
#include <hip/hip_runtime.h>
#include <cstdint>
#include <cstddef>

typedef unsigned short u16;
typedef __bf16 bf16x8 __attribute__((ext_vector_type(8)));
typedef __bf16 bf16x4 __attribute__((ext_vector_type(4)));
typedef float f32x4 __attribute__((ext_vector_type(4)));

#define DEVI __device__ __forceinline__

DEVI u16 f2bf(float f){
  union { float f; unsigned u; } v; v.f = f;
  unsigned r = v.u + 0x7fffu + ((v.u >> 16) & 1u);
  return (u16)(r >> 16);
}

#if defined(__has_builtin)
#if __has_builtin(__builtin_amdgcn_exp2f)
#define EXP2F(x) __builtin_amdgcn_exp2f(x)
#else
#define EXP2F(x) exp2f(x)
#endif
#else
#define EXP2F(x) exp2f(x)
#endif

#define MFMA16(a,b,c) __builtin_amdgcn_mfma_f32_16x16x32_bf16((a),(b),(c),0,0,0)

// async global->LDS, 16B per lane. LDS dest = wave-uniform base + lane*16;
// global src is per-lane (pre-swizzled for bank-conflict-free reads).
DEVI void gload_lds16(const void* g, void* l){
  __builtin_amdgcn_global_load_lds(
      (const __attribute__((address_space(1))) void*)g,
      (__attribute__((address_space(3))) void*)l, 16, 0, 0);
}

#define BARRIER do{ __builtin_amdgcn_s_barrier(); \
    __builtin_amdgcn_sched_barrier(0); }while(0)

// ---------------------------------------------------------------------------
// Workspace layout (bytes).
//  Wt    : bf16 [4][512][512] (n-major)  @ 0         (2097152)
//  Qb    : bf16 [32][2048][64]           @ 2097152   (8388608)  (pre-scaled log2e/8)
//  Kb    : bf16 [32][2048][64]           @ 10485760  (8388608)
//  Vt    : bf16 [32][64][2048]           @ 18874368  (8388608)
//  GOUT  : bf16 [8192][512]              @ 27262976  (8388608)
//  Opart : bf16 [2][8192][512]           @ 35651584  (16777216)
//  Lpart : f32  [2][32][2048]            @ 52428800  (524288)
//  total 52953088 (~50.5 MB)
// ---------------------------------------------------------------------------

// Transpose 4 weight matrices f32 [k][n] -> bf16 [n][k] (K-major for MFMA B).
__global__ void k_prep_w(const float* __restrict__ w0, const float* __restrict__ w1,
                         const float* __restrict__ w2, const float* __restrict__ w3,
                         u16* __restrict__ wt){
  __shared__ u16 tile[64][72];
  int p = blockIdx.z;
  const float* W = (p==0)?w0:((p==1)?w1:((p==2)?w2:w3));
  int k0 = blockIdx.x*64, n0 = blockIdx.y*64;
  int t = threadIdx.x;
  int tr = t >> 4, tc = t & 15;
  #pragma unroll
  for (int pass=0; pass<4; pass++){
    int row = pass*16 + tr;                           // k_local
    float4 a = *(const float4*)(W + (size_t)(k0+row)*512 + n0 + tc*4);
    tile[row][tc*4+0] = f2bf(a.x);
    tile[row][tc*4+1] = f2bf(a.y);
    tile[row][tc*4+2] = f2bf(a.z);
    tile[row][tc*4+3] = f2bf(a.w);
  }
  __syncthreads();
  #pragma unroll
  for (int pass=0; pass<4; pass++){
    int n = pass*16 + tr;                             // n_local
    ushort4 o;
    o.x = tile[tc*4+0][n];
    o.y = tile[tc*4+1][n];
    o.z = tile[tc*4+2][n];
    o.w = tile[tc*4+3][n];
    *(ushort4*)(wt + (size_t)p*262144 + (size_t)(n0+n)*512 + k0 + tc*4) = o;
  }
}

// ---------------------------------------------------------------------------
// QKV projection, occupancy build: BK=32, 3-deep LDS rotation (ONE barrier
// per k-tile; WAR safe because buf[(t+1)%3] == buf[(t-2)%3], freed by
// barrier(t-1)), LDS 48KB -> 3 blocks/CU, grid 768 FULLY resident (no tail).
// A: f32 loads 2 tiles deep (avA/avB ping-pong) -> cvt -> swizzled ds_write.
// B: global_load_lds with pre-swizzled source. Swizzle (64B rows):
// slot' = slot ^ ((row>>1)&3)  (2-way banks on write and read).
// Steady-state vmcnt(6) = waits A(t+1)'s 4 + B(t)'s 2; tails 2 / 0.
// 128x128 tile, 4 waves (2x2), flat grid 768 with XCD decode.
// Q,K -> [b][h][s][64] (Q pre-scaled log2e/8); V -> transposed [b][h][64][s].
// ---------------------------------------------------------------------------
__global__ __launch_bounds__(256)
void k_gemm_qkv(const float* __restrict__ xq, const float* __restrict__ xk,
                const float* __restrict__ xv, const u16* __restrict__ wt,
                const float* __restrict__ bq, const float* __restrict__ bk,
                const float* __restrict__ bv,
                u16* __restrict__ qb, u16* __restrict__ kb, u16* __restrict__ vt){
  int l = threadIdx.x & 63, w = threadIdx.x >> 6;
  int lr = l & 15, lg = l >> 4;
  int f = blockIdx.x;
  int xcd = f & 7, j0 = f >> 3;                 // 96 per XCD
  int pm   = xcd*24 + (j0 >> 2);                // 0..191
  int nblk = j0 & 3;
  int p    = pm >> 6, mblk = pm & 63;
  int wr = w >> 1, wc = w & 1;

  const float* bias = (p==0)?bq:((p==1)?bk:bv);
  float osc = (p==0)? (0.125f*1.44269504088896340736f) : 1.0f;

  const float* Ag32 = ((p==0)?xq:((p==1)?xk:xv)) + (size_t)mblk*128*512;
  const char*  Bg   = (const char*)(wt + (size_t)p*262144 + (size_t)nblk*128*512);

  __shared__ __align__(16) u16 Albuf[3][4096];  // 3 x [128 m][32 k] 8KB
  __shared__ __align__(16) u16 Blbuf[3][4096];  // 3 x [128 n][32 k] 8KB

  int arow0 = w*32 + (l >> 2);                  // A rows: +q*16 per round
  int aslot = l & 3;                            // 8-f32 k-subgroup

  // A-issue: 4 float4 (2 rounds x 2) into named register set
  #define A_ISSUE(tt, av) do{ \
    _Pragma("unroll") \
    for (int q=0; q<2; ++q){ \
      int r = arow0 + q*16; \
      const float* src = Ag32 + (size_t)r*512 + (tt)*32 + aslot*8; \
      av[q*2]   = *(const float4*)src; \
      av[q*2+1] = *(const float4*)(src+4); \
    } }while(0)

  // A-write: cvt f32->bf16, store at swizzled slot (slot ^ ((row>>1)&3))
  #define A_WRITE(av, buf) do{ \
    _Pragma("unroll") \
    for (int q=0; q<2; ++q){ \
      int r = arow0 + q*16; \
      bf16x8 o; \
      o[0]=(__bf16)av[q*2].x;   o[1]=(__bf16)av[q*2].y; \
      o[2]=(__bf16)av[q*2].z;   o[3]=(__bf16)av[q*2].w; \
      o[4]=(__bf16)av[q*2+1].x; o[5]=(__bf16)av[q*2+1].y; \
      o[6]=(__bf16)av[q*2+1].z; o[7]=(__bf16)av[q*2+1].w; \
      *(bf16x8*)((char*)Albuf[buf] + r*64 + ((aslot ^ ((r>>1)&3))<<4)) = o; \
    } }while(0)

  // B-stage: 2 chunks/wave, linear LDS dest, inverse-swizzled global source
  #define B_STAGE(tt, buf) do{ \
    _Pragma("unroll") \
    for (int cc=0; cc<2; ++cc){ \
      int c = w*2 + cc; int row = c*16 + (l>>2); \
      int kg = (l&3) ^ ((row>>1)&3); \
      gload_lds16(Bg + (size_t)row*1024 + (size_t)(tt)*64 + kg*16, \
                  (char*)Blbuf[buf] + c*1024); \
    } }while(0)

  f32x4 acc[4][4] = {};
  float4 avA[4], avB[4];

  // prologue: A(0)->avA written to buf0; A(1)->avB in flight; B(0) staged
  A_ISSUE(0, avA);
  B_STAGE(0, 0);
  A_ISSUE(1, avB);
  asm volatile("s_waitcnt vmcnt(4)" ::: "memory");   // A(0)+B(0) landed
  A_WRITE(avA, 0);
  asm volatile("s_waitcnt lgkmcnt(0)" ::: "memory");
  BARRIER;

  #define QKV_COMPUTE(buf) do{ \
    const char* Ac = (const char*)Albuf[buf]; \
    const char* Bc = (const char*)Blbuf[buf]; \
    bf16x8 af[4], bfr[4]; \
    _Pragma("unroll") \
    for (int i=0;i<4;i++){ \
      int row = wr*64 + i*16 + lr; \
      af[i] = *(const bf16x8*)(Ac + row*64 + ((lg ^ ((row>>1)&3))<<4)); \
    } \
    _Pragma("unroll") \
    for (int j=0;j<4;j++){ \
      int row = wc*64 + j*16 + lr; \
      bfr[j] = *(const bf16x8*)(Bc + row*64 + ((lg ^ ((row>>1)&3))<<4)); \
    } \
    _Pragma("unroll") \
    for (int i=0;i<4;i++) \
      _Pragma("unroll") \
      for (int j=0;j<4;j++) \
        acc[i][j] = MFMA16(af[i], bfr[j], acc[i][j]); \
  }while(0)

  // iter t: issue A(t+2) -> (t even ? avA : avB); B_STAGE(t+1);
  // vmcnt(6) [A(t+1)+B(t) done]; A_WRITE(t+1) from other set; lgkm; barrier;
  // compute(t). Tails: t=14 vmcnt(2), t=15 vmcnt(0).
  #define QKV_ITER(t, AVI, AVW) do{ \
    if ((t) < 14) A_ISSUE((t)+2, AVI); \
    if ((t) < 15) B_STAGE((t)+1, ((t)+1)%3); \
    if ((t) < 14)      asm volatile("s_waitcnt vmcnt(6)" ::: "memory"); \
    else if ((t) < 15) asm volatile("s_waitcnt vmcnt(2)" ::: "memory"); \
    else               asm volatile("s_waitcnt vmcnt(0)" ::: "memory"); \
    if ((t) < 15) A_WRITE(AVW, ((t)+1)%3); \
    asm volatile("s_waitcnt lgkmcnt(0)" ::: "memory"); \
    BARRIER; \
    QKV_COMPUTE((t)%3); \
  }while(0)

  QKV_ITER(0,  avA, avB);
  QKV_ITER(1,  avB, avA);
  QKV_ITER(2,  avA, avB);
  QKV_ITER(3,  avB, avA);
  QKV_ITER(4,  avA, avB);
  QKV_ITER(5,  avB, avA);
  QKV_ITER(6,  avA, avB);
  QKV_ITER(7,  avB, avA);
  QKV_ITER(8,  avA, avB);
  QKV_ITER(9,  avB, avA);
  QKV_ITER(10, avA, avB);
  QKV_ITER(11, avB, avA);
  QKV_ITER(12, avA, avB);
  QKV_ITER(13, avB, avA);
  QKV_ITER(14, avA, avB);
  QKV_ITER(15, avA, avA);

  #undef QKV_ITER
  #undef QKV_COMPUTE
  #undef A_ISSUE
  #undef A_WRITE
  #undef B_STAGE

  int m0 = mblk*128 + wr*64;
  int n0 = nblk*128 + wc*64;
  if (p < 2){
    u16* outp = (p==0)?qb:kb;
    #pragma unroll
    for (int i=0;i<4;i++){
      #pragma unroll
      for (int j=0;j<4;j++){
        int n = n0 + j*16 + lr;
        int h = n >> 6, d = n & 63;
        float bb = bias[n];
        #pragma unroll
        for (int rg=0;rg<4;rg++){
          int m = m0 + i*16 + 4*lg + rg;
          int b = m >> 11, s = m & 2047;
          float val = (acc[i][j][rg] + bb)*osc;
          __bf16 hb = (__bf16)val;
          outp[(((size_t)b*8 + h)*2048 + s)*64 + d] = *(u16*)&hb;
        }
      }
    }
  } else {
    // V: write transposed [bh][d][s]; 4 rg values are consecutive in s.
    #pragma unroll
    for (int i=0;i<4;i++){
      #pragma unroll
      for (int j=0;j<4;j++){
        int n = n0 + j*16 + lr;
        int h = n >> 6, d = n & 63;
        float bb = bias[n];
        int m = m0 + i*16 + 4*lg;
        int b = m >> 11, s = m & 2047;
        ushort4 o;
        #pragma unroll
        for (int rg=0;rg<4;rg++){
          __bf16 hb = (__bf16)(acc[i][j][rg] + bb);
          ((u16*)&o)[rg] = *(u16*)&hb;
        }
        *(ushort4*)(vt + (((size_t)(b*8+h)*64 + d)*2048 + s)) = o;
      }
    }
  }
}

// ---------------------------------------------------------------------------
// Flash attention: 3-deep K/V rotation (one barrier/tile), counted vmcnt(2),
// 8 waves x 32 q-rows, kv-split x2. Fixed-max softmax with M folded out:
// P = exp2(S); row-sum l via ones-MFMA on the matrix pipe.
// Grid 512 flat (8 qt x 2 kv-split x 32 bh, XCD decode). LDS 80KB.
// ---------------------------------------------------------------------------
__global__ __launch_bounds__(512, 4)
void k_attn(const u16* __restrict__ qbuf, const u16* __restrict__ kbuf,
            const u16* __restrict__ vtb, u16* __restrict__ opart,
            float* __restrict__ lpart){
  int l = threadIdx.x & 63, w = threadIdx.x >> 6;   // w in 0..7
  int lr = l & 15, lg = l >> 4;
  int f = blockIdx.x;
  int bh    = (f & 7)*4 + ((f >> 3) & 3);       // 4 bh per XCD
  int rest  = f >> 5;                            // 0..15
  int split = rest & 1;
  int q0    = (rest >> 1)*256 + w*32;
  int b = bh >> 3, h = bh & 7;
  int kvbase = split*1024;

  const u16* Qp = qbuf + ((size_t)bh*2048 + q0)*64;
  const char* Kg = (const char*)(kbuf + (size_t)bh*2048*64) + (size_t)kvbase*128;
  const char* Vg = (const char*)(vtb  + (size_t)bh*64*2048) + (size_t)kvbase*2;

  __shared__ __align__(16) u16 Klds[3][4096];   // 3 x [64 kv][64 d] 8KB
  __shared__ __align__(16) u16 Vlds[3][4096];   // 3 x [64 d][64 kv] 8KB
  __shared__ __align__(16) u16 Plds[8][2048];   // per-wave [32 q][64 kv] 4KB
  u16* Pw = Plds[w];

  int r8 = l >> 3, sl = l & 7;

  // Q fragments: 2 q-subtiles x 2 k-halves
  bf16x8 qf[2][2];
  #pragma unroll
  for (int j=0;j<2;j++)
    #pragma unroll
    for (int kk=0;kk<2;kk++)
      qf[j][kk] = *(const bf16x8*)(Qp + (size_t)(j*16+lr)*64 + kk*32 + lg*8);

  // all-ones B fragment for the row-sum MFMA
  bf16x8 onesf;
  #pragma unroll
  for (int e=0;e<8;e++) onesf[e] = (__bf16)1.0f;

  // prologue: each of the 8 waves stages one 8-row chunk of K and of V
  {
    int row = w*8 + r8;
    int sw = (sl ^ (row & 7)) << 4;
    gload_lds16(Kg + (size_t)row*128 + sw,  (char*)Klds[0] + w*1024);
    gload_lds16(Vg + (size_t)row*4096 + sw, (char*)Vlds[0] + w*1024);
  }

  f32x4 oacc[2][4] = {};
  f32x4 lacc[2] = {};

  int cur = 0;
  for (int t = 0; t < 16; ++t){
    if (t < 15){
      int nxt = (cur == 2) ? 0 : cur + 1;
      int row = w*8 + r8;
      int sw = (sl ^ (row & 7)) << 4;
      gload_lds16(Kg + (size_t)(t+1)*8192 + (size_t)row*128 + sw,
                  (char*)Klds[nxt] + w*1024);
      gload_lds16(Vg + (size_t)(t+1)*128 + (size_t)row*4096 + sw,
                  (char*)Vlds[nxt] + w*1024);
      asm volatile("s_waitcnt vmcnt(2)" ::: "memory");  // tile-t's K+V landed
    } else {
      asm volatile("s_waitcnt vmcnt(0)" ::: "memory");
    }
    BARRIER;                                     // single barrier per tile
    const char* Kc = (const char*)Klds[cur];
    const char* Vc = (const char*)Vlds[cur];
    // --- S^T = K * Q^T (rows = kv, cols = q), log2 units ---
    f32x4 sacc[4][2] = {};
    #pragma unroll
    for (int kk=0;kk<2;kk++){
      bf16x8 kf[4];
      #pragma unroll
      for (int i=0;i<4;i++)
        kf[i] = *(const bf16x8*)(Kc + (i*16+lr)*128 + (((4*kk+lg)^(lr&7))<<4));
      #pragma unroll
      for (int i=0;i<4;i++)
        #pragma unroll
        for (int j=0;j<2;j++)
          sacc[i][j] = MFMA16(kf[i], qf[j][kk], sacc[i][j]);
    }
    // --- P = exp2(S), pack to bf16, per-wave swizzled P-LDS ---
    #pragma unroll
    for (int j=0;j<2;j++){
      int qrow = lr + 16*j;
      #pragma unroll
      for (int i=0;i<4;i++){
        bf16x4 pk;
        #pragma unroll
        for (int rg=0;rg<4;rg++)
          pk[rg] = (__bf16)EXP2F(sacc[i][j][rg]);
        int o    = 8*lg + 32*i;                  // byte offset along kv
        int slot = (o >> 4) ^ (qrow & 7);
        *(bf16x4*)((char*)Pw + qrow*128 + (slot<<4) + (o & 15)) = pk;
      }
    }
    // --- O += P * V ; l += P * ones (row-sum on the matrix pipe) ---
    #pragma unroll
    for (int kk=0;kk<2;kk++){
      bf16x8 pf[2];
      #pragma unroll
      for (int fi=0;fi<2;fi++){
        int qrow = fi*16 + lr;
        int slot = (4*kk + lg) ^ (qrow & 7);
        pf[fi] = *(const bf16x8*)((char*)Pw + qrow*128 + (slot<<4));
      }
      bf16x8 vf[4];
      #pragma unroll
      for (int fj=0;fj<4;fj++)
        vf[fj] = *(const bf16x8*)(Vc + (fj*16+lr)*128 + (((4*kk+lg)^(lr&7))<<4));
      #pragma unroll
      for (int fi=0;fi<2;fi++){
        #pragma unroll
        for (int fj=0;fj<4;fj++)
          oacc[fi][fj] = MFMA16(pf[fi], vf[fj], oacc[fi][fj]);
        lacc[fi] = MFMA16(pf[fi], onesf, lacc[fi]);
      }
    }
    cur = (cur == 2) ? 0 : cur + 1;
  }

  // lacc[fi][rg] = l for q-row fi*16 + 4*lg + rg (all cols equal; take lr==0)
  if (lr == 0){
    #pragma unroll
    for (int fi=0;fi<2;fi++)
      #pragma unroll
      for (int rg=0;rg<4;rg++)
        lpart[((size_t)split*32 + bh)*2048 + q0 + fi*16 + 4*lg + rg] = lacc[fi][rg];
  }
  u16* op = opart + (size_t)split*8192*512;
  #pragma unroll
  for (int fi=0;fi<2;fi++){
    #pragma unroll
    for (int fj=0;fj<4;fj++){
      int col = h*64 + fj*16 + lr;
      #pragma unroll
      for (int rg=0;rg<4;rg++){
        int qg = q0 + fi*16 + 4*lg + rg;
        __bf16 hb = (__bf16)oacc[fi][fj][rg];
        op[((size_t)(b*2048 + qg))*512 + col] = *(u16*)&hb;
      }
    }
  }
}

// ---------------------------------------------------------------------------
// Output projection GEMM with the kv-split combine fused into reg-staged A
// (R10-proven). Per iter: issue A(t+1) regs (8 vmem) + B(t+1) gload_lds (4)
// -> vmcnt(12) waits B(t) -> barrier -> compute(t) -> vmcnt(4) waits A(t+1)
// -> combine+ds_write -> lgkmcnt(0) -> barrier.
// 64x128 tile, BK=64, 4 waves, grid 512 flat with XCD decode.
// ---------------------------------------------------------------------------
__global__ __launch_bounds__(256)
void k_gemm_o(const u16* __restrict__ op0, const u16* __restrict__ op1,
              const float* __restrict__ lpart, const u16* __restrict__ wto,
              u16* __restrict__ gout){
  int l = threadIdx.x & 63, w = threadIdx.x >> 6;
  int lr = l & 15, lg = l >> 4;
  int f = blockIdx.x;
  int xcd = f & 7, j0 = f >> 3;                 // 64 per XCD
  int mblk = xcd*16 + (j0 >> 2);                // 0..127 (64-row blocks)
  int nblk = j0 & 3;                            // 0..3   (128-col blocks)
  int wr = w & 1, wc = w >> 1;                  // wave: 32m x 64n

  int bb8 = (mblk >> 5) * 8;                    // b*8 (block-uniform)
  int qbase = (mblk & 31) * 64;                 // q of row 0 (block-uniform)

  const u16* Ag0 = op0 + (size_t)mblk*64*512;
  const u16* Ag1 = op1 + (size_t)mblk*64*512;
  const char* Bg = (const char*)(wto + (size_t)nblk*128*512);

  __shared__ __align__(16) u16 Albuf[2][4096];  // 2 x [64 m][64 k] 8KB
  __shared__ __align__(16) u16 Blbuf[2][8192];  // 2 x [128 n][64 k] 16KB

  int r8 = l >> 3, sl = l & 7;

  // A-issue: load op0/op1 chunks + lpart scalars into registers (tile tt)
  bf16x8 a0v[2], a1v[2]; float l0v[2], l1v[2];
  #define A_ISSUE(tt) do{ \
    _Pragma("unroll") \
    for (int cc=0; cc<2; ++cc){ \
      int c = w*2 + cc; int row = c*8 + r8; \
      int ssrc = sl ^ (row & 7); \
      a0v[cc] = *(const bf16x8*)(Ag0 + (size_t)row*512 + (tt)*64 + ssrc*8); \
      a1v[cc] = *(const bf16x8*)(Ag1 + (size_t)row*512 + (tt)*64 + ssrc*8); \
      int q = qbase + row; \
      l0v[cc] = lpart[(size_t)(bb8 + (tt))*2048 + q]; \
      l1v[cc] = lpart[(size_t)(32 + bb8 + (tt))*2048 + q]; \
    } }while(0)

  // A-write: combine and store to LINEAR dest in Albuf[buf]
  #define A_WRITE(buf) do{ \
    _Pragma("unroll") \
    for (int cc=0; cc<2; ++cc){ \
      int c = w*2 + cc; \
      float inv = 1.f / (l0v[cc] + l1v[cc]); \
      bf16x8 r; \
      _Pragma("unroll") \
      for (int e=0;e<8;e++) \
        r[e] = (__bf16)(((float)a0v[cc][e] + (float)a1v[cc][e]) * inv); \
      *(bf16x8*)((char*)Albuf[buf] + c*1024 + r8*128 + sl*16) = r; \
    } }while(0)

  #define B_STAGE(tt, buf) do{ \
    _Pragma("unroll") \
    for (int cc=0; cc<4; ++cc){ \
      int c = w*4 + cc; int row = c*8 + r8; \
      int sw = (sl ^ (row & 7)) << 4; \
      gload_lds16(Bg + (size_t)row*1024 + (size_t)(tt)*128 + sw, (char*)Blbuf[buf] + c*1024); \
    } }while(0)

  // prologue: A(0) regs + B(0); combine-write A(0)
  A_ISSUE(0);
  B_STAGE(0, 0);
  asm volatile("s_waitcnt vmcnt(4)" ::: "memory");   // A(0)'s 8 landed
  A_WRITE(0);
  asm volatile("s_waitcnt lgkmcnt(0)" ::: "memory");

  f32x4 acc[2][4] = {};
  for (int t = 0; t < 8; ++t){
    int cur = t & 1;
    if (t < 7){
      A_ISSUE(t+1);
      B_STAGE(t+1, cur^1);
      asm volatile("s_waitcnt vmcnt(12)" ::: "memory"); // B(t)'s 4 landed
    } else {
      asm volatile("s_waitcnt vmcnt(0)" ::: "memory");
    }
    BARRIER;
    const char* Ac = (const char*)Albuf[cur];
    const char* Bc = (const char*)Blbuf[cur];
    #pragma unroll
    for (int kk=0;kk<2;kk++){
      int ks = ((kk*4 + lg) ^ (lr & 7)) << 4;
      bf16x8 af[2], bfr[4];
      #pragma unroll
      for (int i=0;i<2;i++)
        af[i]  = *(const bf16x8*)(Ac + (wr*32 + i*16 + lr)*128 + ks);
      #pragma unroll
      for (int j=0;j<4;j++)
        bfr[j] = *(const bf16x8*)(Bc + (wc*64 + j*16 + lr)*128 + ks);
      #pragma unroll
      for (int i=0;i<2;i++)
        #pragma unroll
        for (int j=0;j<4;j++)
          acc[i][j] = MFMA16(af[i], bfr[j], acc[i][j]);
    }
    if (t < 7){
      asm volatile("s_waitcnt vmcnt(4)" ::: "memory"); // A(t+1)'s 8 landed
      A_WRITE(cur^1);
      asm volatile("s_waitcnt lgkmcnt(0)" ::: "memory");
      BARRIER;                       // WAR + A-write visibility
    }
  }
  #undef A_ISSUE
  #undef A_WRITE
  #undef B_STAGE

  int m0 = mblk*64 + wr*32;
  int n0 = nblk*128 + wc*64;
  #pragma unroll
  for (int i=0;i<2;i++){
    #pragma unroll
    for (int j=0;j<4;j++){
      int n = n0 + j*16 + lr;
      #pragma unroll
      for (int rg=0;rg<4;rg++){
        int m = m0 + i*16 + 4*lg + rg;
        __bf16 hb = (__bf16)acc[i][j][rg];
        gout[(size_t)m*512 + n] = *(u16*)&hb;
      }
    }
  }
}

// LayerNorm pass: out = LN(gout + bo + resid) * g + beta. One wave per row,
// fully vectorized; grid 2048 x 256 (8192 waves = 8192 rows).
__global__ __launch_bounds__(256)
void k_ln(const u16* __restrict__ gout, const float* __restrict__ bo,
          const float* __restrict__ resid, const float* __restrict__ g,
          const float* __restrict__ beta, float* __restrict__ out){
  int gid  = blockIdx.x*256 + threadIdx.x;
  int row  = gid >> 6;
  int lane = gid & 63;
  int c0 = lane*8;
  bf16x8 a = *(const bf16x8*)(gout + (size_t)row*512 + c0);
  float4 r0 = *(const float4*)(resid + (size_t)row*512 + c0);
  float4 r1 = *(const float4*)(resid + (size_t)row*512 + c0 + 4);
  float4 b0 = *(const float4*)(bo + c0);
  float4 b1 = *(const float4*)(bo + c0 + 4);
  float v[8];
  v[0]=(float)a[0]+b0.x+r0.x; v[1]=(float)a[1]+b0.y+r0.y;
  v[2]=(float)a[2]+b0.z+r0.z; v[3]=(float)a[3]+b0.w+r0.w;
  v[4]=(float)a[4]+b1.x+r1.x; v[5]=(float)a[5]+b1.y+r1.y;
  v[6]=(float)a[6]+b1.z+r1.z; v[7]=(float)a[7]+b1.w+r1.w;
  float s1 = 0.f, s2 = 0.f;
  #pragma unroll
  for (int e=0;e<8;e++){ s1 += v[e]; s2 += v[e]*v[e]; }
  #pragma unroll
  for (int mk=1; mk<64; mk<<=1){
    s1 += __shfl_xor(s1, mk);
    s2 += __shfl_xor(s2, mk);
  }
  float mu   = s1 * (1.f/512.f);
  float var  = s2 * (1.f/512.f) - mu*mu;
  float rstd = rsqrtf(var + 1e-5f);
  float4 g0 = *(const float4*)(g + c0);
  float4 g1 = *(const float4*)(g + c0 + 4);
  float4 e0 = *(const float4*)(beta + c0);
  float4 e1 = *(const float4*)(beta + c0 + 4);
  float4 o0, o1;
  o0.x=(v[0]-mu)*rstd*g0.x+e0.x; o0.y=(v[1]-mu)*rstd*g0.y+e0.y;
  o0.z=(v[2]-mu)*rstd*g0.z+e0.z; o0.w=(v[3]-mu)*rstd*g0.w+e0.w;
  o1.x=(v[4]-mu)*rstd*g1.x+e1.x; o1.y=(v[5]-mu)*rstd*g1.y+e1.y;
  o1.z=(v[6]-mu)*rstd*g1.z+e1.z; o1.w=(v[7]-mu)*rstd*g1.w+e1.w;
  *(float4*)(out + (size_t)row*512 + c0)     = o0;
  *(float4*)(out + (size_t)row*512 + c0 + 4) = o1;
}

extern "C" void kernel_launch(void* const* d_in, const int* in_sizes, int n_in,
                              void* d_out, int out_size, void* d_ws, size_t ws_size,
                              hipStream_t stream){
  const float* q   = (const float*)d_in[0];
  const float* k   = (const float*)d_in[1];
  const float* v   = (const float*)d_in[2];
  const float* wq  = (const float*)d_in[3];
  const float* bq  = (const float*)d_in[4];
  const float* wk  = (const float*)d_in[5];
  const float* bk  = (const float*)d_in[6];
  const float* wv  = (const float*)d_in[7];
  const float* bv  = (const float*)d_in[8];
  const float* wo  = (const float*)d_in[9];
  const float* bo  = (const float*)d_in[10];
  const float* lng = (const float*)d_in[11];
  const float* lnb = (const float*)d_in[12];
  float* out = (float*)d_out;
  char* ws = (char*)d_ws;
  u16*   wt    = (u16*)(ws + 0);
  u16*   qb    = (u16*)(ws + 2097152);
  u16*   kb    = (u16*)(ws + 10485760);
  u16*   vt    = (u16*)(ws + 18874368);
  u16*   gout  = (u16*)(ws + 27262976);
  u16*   opart = (u16*)(ws + 35651584);
  float* lpart = (float*)(ws + 52428800);

  k_prep_w<<<dim3(8,8,4), 256, 0, stream>>>(wq, wk, wv, wo, wt);
  k_gemm_qkv<<<768, 256, 0, stream>>>(q, k, v, wt, bq, bk, bv, qb, kb, vt);
  k_attn<<<512, 512, 0, stream>>>(qb, kb, vt, opart, lpart);
  k_gemm_o<<<512, 256, 0, stream>>>(opart, opart + (size_t)8192*512, lpart,
                                    wt + 3*262144, gout);
  k_ln<<<2048, 256, 0, stream>>>(gout, bo, q, lng, lnb, out);
}

// Round 17
// 97.879 us; speedup vs baseline: 1.0182x; 1.0182x over previous
//
#include <hip/hip_runtime.h>
#include <cstdint>
#include <cstddef>

typedef unsigned short u16;
typedef __bf16 bf16x8 __attribute__((ext_vector_type(8)));
typedef __bf16 bf16x4 __attribute__((ext_vector_type(4)));
typedef float f32x4 __attribute__((ext_vector_type(4)));

#define DEVI __device__ __forceinline__

DEVI u16 f2bf(float f){
  union { float f; unsigned u; } v; v.f = f;
  unsigned r = v.u + 0x7fffu + ((v.u >> 16) & 1u);
  return (u16)(r >> 16);
}

#if defined(__has_builtin)
#if __has_builtin(__builtin_amdgcn_exp2f)
#define EXP2F(x) __builtin_amdgcn_exp2f(x)
#else
#define EXP2F(x) exp2f(x)
#endif
#else
#define EXP2F(x) exp2f(x)
#endif

#define MFMA16(a,b,c) __builtin_amdgcn_mfma_f32_16x16x32_bf16((a),(b),(c),0,0,0)

// async global->LDS, 16B per lane. LDS dest = wave-uniform base + lane*16;
// global src is per-lane (pre-swizzled for bank-conflict-free reads).
DEVI void gload_lds16(const void* g, void* l){
  __builtin_amdgcn_global_load_lds(
      (const __attribute__((address_space(1))) void*)g,
      (__attribute__((address_space(3))) void*)l, 16, 0, 0);
}

#define BARRIER do{ __builtin_amdgcn_s_barrier(); \
    __builtin_amdgcn_sched_barrier(0); }while(0)

// ---------------------------------------------------------------------------
// Workspace layout (bytes).
//  Wt    : bf16 [4][512][512] (n-major)  @ 0         (2097152)
//  Qb    : bf16 [32][2048][64]           @ 2097152   (8388608)  (pre-scaled log2e/8)
//  Kb    : bf16 [32][2048][64]           @ 10485760  (8388608)
//  Vt    : bf16 [32][64][2048]           @ 18874368  (8388608)
//  GOUT  : bf16 [8192][512]              @ 27262976  (8388608)
//  Opart : bf16 [2][8192][512]           @ 35651584  (16777216)
//  Lpart : f32  [2][32][2048]            @ 52428800  (524288)
//  total 52953088 (~50.5 MB)
// ---------------------------------------------------------------------------

// Transpose 4 weight matrices f32 [k][n] -> bf16 [n][k] (K-major for MFMA B).
__global__ void k_prep_w(const float* __restrict__ w0, const float* __restrict__ w1,
                         const float* __restrict__ w2, const float* __restrict__ w3,
                         u16* __restrict__ wt){
  __shared__ u16 tile[64][72];
  int p = blockIdx.z;
  const float* W = (p==0)?w0:((p==1)?w1:((p==2)?w2:w3));
  int k0 = blockIdx.x*64, n0 = blockIdx.y*64;
  int t = threadIdx.x;
  int tr = t >> 4, tc = t & 15;
  #pragma unroll
  for (int pass=0; pass<4; pass++){
    int row = pass*16 + tr;                           // k_local
    float4 a = *(const float4*)(W + (size_t)(k0+row)*512 + n0 + tc*4);
    tile[row][tc*4+0] = f2bf(a.x);
    tile[row][tc*4+1] = f2bf(a.y);
    tile[row][tc*4+2] = f2bf(a.z);
    tile[row][tc*4+3] = f2bf(a.w);
  }
  __syncthreads();
  #pragma unroll
  for (int pass=0; pass<4; pass++){
    int n = pass*16 + tr;                             // n_local
    ushort4 o;
    o.x = tile[tc*4+0][n];
    o.y = tile[tc*4+1][n];
    o.z = tile[tc*4+2][n];
    o.w = tile[tc*4+3][n];
    *(ushort4*)(wt + (size_t)p*262144 + (size_t)(n0+n)*512 + k0 + tc*4) = o;
  }
}

// ---------------------------------------------------------------------------
// QKV projection, R15-proven schedule, 128x64 tile (B-side halved so LDS =
// 48KB -> 3 blocks/CU resident; grid 1536 = 6 blocks/CU queued, no tail).
// A reg-staged (8x float4 -> cvt -> swizzled ds_write); B via global_load_lds.
// Counted vmcnt: prologue waits A(0) with vmcnt(2); steady vmcnt(10) waits
// B(t) [outstanding B(t)2 + A(t+1)8 + B(t+1)2 = 12, leave 10]; post-compute
// vmcnt(2) waits A(t+1) [leave B(t+1) 2].
// 4 waves (2m x 2n -> 64m x 32n each), flat grid 1536 with XCD decode.
// Q,K -> [b][h][s][64] (Q pre-scaled log2e/8); V -> transposed [b][h][64][s].
// ---------------------------------------------------------------------------
__global__ __launch_bounds__(256)
void k_gemm_qkv(const float* __restrict__ xq, const float* __restrict__ xk,
                const float* __restrict__ xv, const u16* __restrict__ wt,
                const float* __restrict__ bq, const float* __restrict__ bk,
                const float* __restrict__ bv,
                u16* __restrict__ qb, u16* __restrict__ kb, u16* __restrict__ vt){
  int l = threadIdx.x & 63, w = threadIdx.x >> 6;
  int lr = l & 15, lg = l >> 4;
  int f = blockIdx.x;
  int xcd = f & 7, j0 = f >> 3;                 // 192 per XCD
  int pm   = xcd*24 + (j0 >> 3);                // 0..191 (p, mblk)
  int nblk = j0 & 7;                            // 0..7 (64-col blocks)
  int p    = pm >> 6, mblk = pm & 63;
  int wr = w >> 1, wc = w & 1;

  const float* bias = (p==0)?bq:((p==1)?bk:bv);
  float osc = (p==0)? (0.125f*1.44269504088896340736f) : 1.0f;

  const float* Ag32 = ((p==0)?xq:((p==1)?xk:xv)) + (size_t)mblk*128*512;
  const char*  Bg   = (const char*)(wt + (size_t)p*262144 + (size_t)nblk*64*512);

  __shared__ __align__(16) u16 Albuf[2][8192];  // 2 x [128 m][64 k] 16KB
  __shared__ __align__(16) u16 Blbuf[2][4096];  // 2 x [64 n][64 k] 8KB

  int r8 = l >> 3, sl = l & 7;                  // chunk-local row / 16B slot
  int ar = w*8 + r8;                            // A base row; rounds add p4*32
  int as = sl;                                  // A k-slot (8 bf16)

  // A-issue: 8 float4 loads (4 rounds x 2), rows ar+p4*32, k-cols as*8..+7
  float4 av[8];
  #define A_ISSUE(tt) do{ \
    _Pragma("unroll") \
    for (int p4=0; p4<4; ++p4){ \
      int r = ar + p4*32; \
      const float* src = Ag32 + (size_t)r*512 + (tt)*64 + as*8; \
      av[p4*2]   = *(const float4*)src; \
      av[p4*2+1] = *(const float4*)(src+4); \
    } }while(0)

  // A-write: cvt f32->bf16, store to the XOR-swizzled slot the reads expect.
  #define A_WRITE(buf) do{ \
    _Pragma("unroll") \
    for (int p4=0; p4<4; ++p4){ \
      int r = ar + p4*32; \
      bf16x8 o; \
      o[0]=(__bf16)av[p4*2].x;   o[1]=(__bf16)av[p4*2].y; \
      o[2]=(__bf16)av[p4*2].z;   o[3]=(__bf16)av[p4*2].w; \
      o[4]=(__bf16)av[p4*2+1].x; o[5]=(__bf16)av[p4*2+1].y; \
      o[6]=(__bf16)av[p4*2+1].z; o[7]=(__bf16)av[p4*2+1].w; \
      *(bf16x8*)((char*)Albuf[buf] + r*128 + ((as ^ (r & 7)) << 4)) = o; \
    } }while(0)

  // B-stage: 8 chunks of 8 rows x 128B total, 2 per wave
  #define B_STAGE(tt, buf) do{ \
    _Pragma("unroll") \
    for (int cc=0; cc<2; ++cc){ \
      int c = w*2 + cc; int row = c*8 + r8; \
      int sw = (sl ^ (row & 7)) << 4; \
      gload_lds16(Bg + (size_t)row*1024 + (size_t)(tt)*128 + sw, (char*)Blbuf[buf] + c*1024); \
    } }while(0)

  // prologue
  A_ISSUE(0);
  B_STAGE(0, 0);
  asm volatile("s_waitcnt vmcnt(2)" ::: "memory");   // A(0)'s 8 landed
  A_WRITE(0);
  asm volatile("s_waitcnt lgkmcnt(0)" ::: "memory");

  f32x4 acc[4][2] = {};
  for (int t = 0; t < 8; ++t){
    int cur = t & 1;
    if (t < 7){
      A_ISSUE(t+1);
      B_STAGE(t+1, cur^1);
      asm volatile("s_waitcnt vmcnt(10)" ::: "memory"); // B(t)'s 2 landed
    } else {
      asm volatile("s_waitcnt vmcnt(0)" ::: "memory");
    }
    BARRIER;
    const char* Ac = (const char*)Albuf[cur];
    const char* Bc = (const char*)Blbuf[cur];
    #pragma unroll
    for (int kk=0;kk<2;kk++){
      int ks = ((kk*4 + lg) ^ (lr & 7)) << 4;
      bf16x8 af[4], bfr[2];
      #pragma unroll
      for (int i=0;i<4;i++)
        af[i]  = *(const bf16x8*)(Ac + (wr*64 + i*16 + lr)*128 + ks);
      #pragma unroll
      for (int j=0;j<2;j++)
        bfr[j] = *(const bf16x8*)(Bc + (wc*32 + j*16 + lr)*128 + ks);
      #pragma unroll
      for (int i=0;i<4;i++)
        #pragma unroll
        for (int j=0;j<2;j++)
          acc[i][j] = MFMA16(af[i], bfr[j], acc[i][j]);
    }
    if (t < 7){
      asm volatile("s_waitcnt vmcnt(2)" ::: "memory"); // A(t+1)'s 8 landed
      A_WRITE(cur^1);
      asm volatile("s_waitcnt lgkmcnt(0)" ::: "memory");
      BARRIER;                       // WAR + A-write visibility
    }
  }
  #undef A_ISSUE
  #undef A_WRITE
  #undef B_STAGE

  int m0 = mblk*128 + wr*64;
  int n0 = nblk*64 + wc*32;
  if (p < 2){
    u16* outp = (p==0)?qb:kb;
    #pragma unroll
    for (int i=0;i<4;i++){
      #pragma unroll
      for (int j=0;j<2;j++){
        int n = n0 + j*16 + lr;
        int h = n >> 6, d = n & 63;
        float bb = bias[n];
        #pragma unroll
        for (int rg=0;rg<4;rg++){
          int m = m0 + i*16 + 4*lg + rg;
          int b = m >> 11, s = m & 2047;
          float val = (acc[i][j][rg] + bb)*osc;
          __bf16 hb = (__bf16)val;
          outp[(((size_t)b*8 + h)*2048 + s)*64 + d] = *(u16*)&hb;
        }
      }
    }
  } else {
    // V: write transposed [bh][d][s]; 4 rg values are consecutive in s.
    #pragma unroll
    for (int i=0;i<4;i++){
      #pragma unroll
      for (int j=0;j<2;j++){
        int n = n0 + j*16 + lr;
        int h = n >> 6, d = n & 63;
        float bb = bias[n];
        int m = m0 + i*16 + 4*lg;
        int b = m >> 11, s = m & 2047;
        ushort4 o;
        #pragma unroll
        for (int rg=0;rg<4;rg++){
          __bf16 hb = (__bf16)(acc[i][j][rg] + bb);
          ((u16*)&o)[rg] = *(u16*)&hb;
        }
        *(ushort4*)(vt + (((size_t)(b*8+h)*64 + d)*2048 + s)) = o;
      }
    }
  }
}

// ---------------------------------------------------------------------------
// Flash attention: 3-deep K/V rotation (one barrier/tile), counted vmcnt(2),
// 8 waves x 32 q-rows, kv-split x2. Fixed-max softmax with M folded out:
// P = exp2(S); row-sum l via ones-MFMA on the matrix pipe.
// Grid 512 flat (8 qt x 2 kv-split x 32 bh, XCD decode). LDS 80KB.
// ---------------------------------------------------------------------------
__global__ __launch_bounds__(512, 4)
void k_attn(const u16* __restrict__ qbuf, const u16* __restrict__ kbuf,
            const u16* __restrict__ vtb, u16* __restrict__ opart,
            float* __restrict__ lpart){
  int l = threadIdx.x & 63, w = threadIdx.x >> 6;   // w in 0..7
  int lr = l & 15, lg = l >> 4;
  int f = blockIdx.x;
  int bh    = (f & 7)*4 + ((f >> 3) & 3);       // 4 bh per XCD
  int rest  = f >> 5;                            // 0..15
  int split = rest & 1;
  int q0    = (rest >> 1)*256 + w*32;
  int b = bh >> 3, h = bh & 7;
  int kvbase = split*1024;

  const u16* Qp = qbuf + ((size_t)bh*2048 + q0)*64;
  const char* Kg = (const char*)(kbuf + (size_t)bh*2048*64) + (size_t)kvbase*128;
  const char* Vg = (const char*)(vtb  + (size_t)bh*64*2048) + (size_t)kvbase*2;

  __shared__ __align__(16) u16 Klds[3][4096];   // 3 x [64 kv][64 d] 8KB
  __shared__ __align__(16) u16 Vlds[3][4096];   // 3 x [64 d][64 kv] 8KB
  __shared__ __align__(16) u16 Plds[8][2048];   // per-wave [32 q][64 kv] 4KB
  u16* Pw = Plds[w];

  int r8 = l >> 3, sl = l & 7;

  // Q fragments: 2 q-subtiles x 2 k-halves
  bf16x8 qf[2][2];
  #pragma unroll
  for (int j=0;j<2;j++)
    #pragma unroll
    for (int kk=0;kk<2;kk++)
      qf[j][kk] = *(const bf16x8*)(Qp + (size_t)(j*16+lr)*64 + kk*32 + lg*8);

  // all-ones B fragment for the row-sum MFMA
  bf16x8 onesf;
  #pragma unroll
  for (int e=0;e<8;e++) onesf[e] = (__bf16)1.0f;

  // prologue: each of the 8 waves stages one 8-row chunk of K and of V
  {
    int row = w*8 + r8;
    int sw = (sl ^ (row & 7)) << 4;
    gload_lds16(Kg + (size_t)row*128 + sw,  (char*)Klds[0] + w*1024);
    gload_lds16(Vg + (size_t)row*4096 + sw, (char*)Vlds[0] + w*1024);
  }

  f32x4 oacc[2][4] = {};
  f32x4 lacc[2] = {};

  int cur = 0;
  for (int t = 0; t < 16; ++t){
    if (t < 15){
      int nxt = (cur == 2) ? 0 : cur + 1;
      int row = w*8 + r8;
      int sw = (sl ^ (row & 7)) << 4;
      gload_lds16(Kg + (size_t)(t+1)*8192 + (size_t)row*128 + sw,
                  (char*)Klds[nxt] + w*1024);
      gload_lds16(Vg + (size_t)(t+1)*128 + (size_t)row*4096 + sw,
                  (char*)Vlds[nxt] + w*1024);
      asm volatile("s_waitcnt vmcnt(2)" ::: "memory");  // tile-t's K+V landed
    } else {
      asm volatile("s_waitcnt vmcnt(0)" ::: "memory");
    }
    BARRIER;                                     // single barrier per tile
    const char* Kc = (const char*)Klds[cur];
    const char* Vc = (const char*)Vlds[cur];
    // --- S^T = K * Q^T (rows = kv, cols = q), log2 units ---
    f32x4 sacc[4][2] = {};
    #pragma unroll
    for (int kk=0;kk<2;kk++){
      bf16x8 kf[4];
      #pragma unroll
      for (int i=0;i<4;i++)
        kf[i] = *(const bf16x8*)(Kc + (i*16+lr)*128 + (((4*kk+lg)^(lr&7))<<4));
      #pragma unroll
      for (int i=0;i<4;i++)
        #pragma unroll
        for (int j=0;j<2;j++)
          sacc[i][j] = MFMA16(kf[i], qf[j][kk], sacc[i][j]);
    }
    // --- P = exp2(S), pack to bf16, per-wave swizzled P-LDS ---
    #pragma unroll
    for (int j=0;j<2;j++){
      int qrow = lr + 16*j;
      #pragma unroll
      for (int i=0;i<4;i++){
        bf16x4 pk;
        #pragma unroll
        for (int rg=0;rg<4;rg++)
          pk[rg] = (__bf16)EXP2F(sacc[i][j][rg]);
        int o    = 8*lg + 32*i;                  // byte offset along kv
        int slot = (o >> 4) ^ (qrow & 7);
        *(bf16x4*)((char*)Pw + qrow*128 + (slot<<4) + (o & 15)) = pk;
      }
    }
    // --- O += P * V ; l += P * ones (row-sum on the matrix pipe) ---
    #pragma unroll
    for (int kk=0;kk<2;kk++){
      bf16x8 pf[2];
      #pragma unroll
      for (int fi=0;fi<2;fi++){
        int qrow = fi*16 + lr;
        int slot = (4*kk + lg) ^ (qrow & 7);
        pf[fi] = *(const bf16x8*)((char*)Pw + qrow*128 + (slot<<4));
      }
      bf16x8 vf[4];
      #pragma unroll
      for (int fj=0;fj<4;fj++)
        vf[fj] = *(const bf16x8*)(Vc + (fj*16+lr)*128 + (((4*kk+lg)^(lr&7))<<4));
      #pragma unroll
      for (int fi=0;fi<2;fi++){
        #pragma unroll
        for (int fj=0;fj<4;fj++)
          oacc[fi][fj] = MFMA16(pf[fi], vf[fj], oacc[fi][fj]);
        lacc[fi] = MFMA16(pf[fi], onesf, lacc[fi]);
      }
    }
    cur = (cur == 2) ? 0 : cur + 1;
  }

  // lacc[fi][rg] = l for q-row fi*16 + 4*lg + rg (all cols equal; take lr==0)
  if (lr == 0){
    #pragma unroll
    for (int fi=0;fi<2;fi++)
      #pragma unroll
      for (int rg=0;rg<4;rg++)
        lpart[((size_t)split*32 + bh)*2048 + q0 + fi*16 + 4*lg + rg] = lacc[fi][rg];
  }
  u16* op = opart + (size_t)split*8192*512;
  #pragma unroll
  for (int fi=0;fi<2;fi++){
    #pragma unroll
    for (int fj=0;fj<4;fj++){
      int col = h*64 + fj*16 + lr;
      #pragma unroll
      for (int rg=0;rg<4;rg++){
        int qg = q0 + fi*16 + 4*lg + rg;
        __bf16 hb = (__bf16)oacc[fi][fj][rg];
        op[((size_t)(b*2048 + qg))*512 + col] = *(u16*)&hb;
      }
    }
  }
}

// ---------------------------------------------------------------------------
// Output projection GEMM with the kv-split combine fused into reg-staged A
// (R10-proven). Per iter: issue A(t+1) regs (8 vmem) + B(t+1) gload_lds (4)
// -> vmcnt(12) waits B(t) -> barrier -> compute(t) -> vmcnt(4) waits A(t+1)
// -> combine+ds_write -> lgkmcnt(0) -> barrier.
// 64x128 tile, BK=64, 4 waves, grid 512 flat with XCD decode.
// ---------------------------------------------------------------------------
__global__ __launch_bounds__(256)
void k_gemm_o(const u16* __restrict__ op0, const u16* __restrict__ op1,
              const float* __restrict__ lpart, const u16* __restrict__ wto,
              u16* __restrict__ gout){
  int l = threadIdx.x & 63, w = threadIdx.x >> 6;
  int lr = l & 15, lg = l >> 4;
  int f = blockIdx.x;
  int xcd = f & 7, j0 = f >> 3;                 // 64 per XCD
  int mblk = xcd*16 + (j0 >> 2);                // 0..127 (64-row blocks)
  int nblk = j0 & 3;                            // 0..3   (128-col blocks)
  int wr = w & 1, wc = w >> 1;                  // wave: 32m x 64n

  int bb8 = (mblk >> 5) * 8;                    // b*8 (block-uniform)
  int qbase = (mblk & 31) * 64;                 // q of row 0 (block-uniform)

  const u16* Ag0 = op0 + (size_t)mblk*64*512;
  const u16* Ag1 = op1 + (size_t)mblk*64*512;
  const char* Bg = (const char*)(wto + (size_t)nblk*128*512);

  __shared__ __align__(16) u16 Albuf[2][4096];  // 2 x [64 m][64 k] 8KB
  __shared__ __align__(16) u16 Blbuf[2][8192];  // 2 x [128 n][64 k] 16KB

  int r8 = l >> 3, sl = l & 7;

  // A-issue: load op0/op1 chunks + lpart scalars into registers (tile tt)
  bf16x8 a0v[2], a1v[2]; float l0v[2], l1v[2];
  #define A_ISSUE(tt) do{ \
    _Pragma("unroll") \
    for (int cc=0; cc<2; ++cc){ \
      int c = w*2 + cc; int row = c*8 + r8; \
      int ssrc = sl ^ (row & 7); \
      a0v[cc] = *(const bf16x8*)(Ag0 + (size_t)row*512 + (tt)*64 + ssrc*8); \
      a1v[cc] = *(const bf16x8*)(Ag1 + (size_t)row*512 + (tt)*64 + ssrc*8); \
      int q = qbase + row; \
      l0v[cc] = lpart[(size_t)(bb8 + (tt))*2048 + q]; \
      l1v[cc] = lpart[(size_t)(32 + bb8 + (tt))*2048 + q]; \
    } }while(0)

  // A-write: combine and store to LINEAR dest in Albuf[buf]
  #define A_WRITE(buf) do{ \
    _Pragma("unroll") \
    for (int cc=0; cc<2; ++cc){ \
      int c = w*2 + cc; \
      float inv = 1.f / (l0v[cc] + l1v[cc]); \
      bf16x8 r; \
      _Pragma("unroll") \
      for (int e=0;e<8;e++) \
        r[e] = (__bf16)(((float)a0v[cc][e] + (float)a1v[cc][e]) * inv); \
      *(bf16x8*)((char*)Albuf[buf] + c*1024 + r8*128 + sl*16) = r; \
    } }while(0)

  #define B_STAGE(tt, buf) do{ \
    _Pragma("unroll") \
    for (int cc=0; cc<4; ++cc){ \
      int c = w*4 + cc; int row = c*8 + r8; \
      int sw = (sl ^ (row & 7)) << 4; \
      gload_lds16(Bg + (size_t)row*1024 + (size_t)(tt)*128 + sw, (char*)Blbuf[buf] + c*1024); \
    } }while(0)

  // prologue: A(0) regs + B(0); combine-write A(0)
  A_ISSUE(0);
  B_STAGE(0, 0);
  asm volatile("s_waitcnt vmcnt(4)" ::: "memory");   // A(0)'s 8 landed
  A_WRITE(0);
  asm volatile("s_waitcnt lgkmcnt(0)" ::: "memory");

  f32x4 acc[2][4] = {};
  for (int t = 0; t < 8; ++t){
    int cur = t & 1;
    if (t < 7){
      A_ISSUE(t+1);
      B_STAGE(t+1, cur^1);
      asm volatile("s_waitcnt vmcnt(12)" ::: "memory"); // B(t)'s 4 landed
    } else {
      asm volatile("s_waitcnt vmcnt(0)" ::: "memory");
    }
    BARRIER;
    const char* Ac = (const char*)Albuf[cur];
    const char* Bc = (const char*)Blbuf[cur];
    #pragma unroll
    for (int kk=0;kk<2;kk++){
      int ks = ((kk*4 + lg) ^ (lr & 7)) << 4;
      bf16x8 af[2], bfr[4];
      #pragma unroll
      for (int i=0;i<2;i++)
        af[i]  = *(const bf16x8*)(Ac + (wr*32 + i*16 + lr)*128 + ks);
      #pragma unroll
      for (int j=0;j<4;j++)
        bfr[j] = *(const bf16x8*)(Bc + (wc*64 + j*16 + lr)*128 + ks);
      #pragma unroll
      for (int i=0;i<2;i++)
        #pragma unroll
        for (int j=0;j<4;j++)
          acc[i][j] = MFMA16(af[i], bfr[j], acc[i][j]);
    }
    if (t < 7){
      asm volatile("s_waitcnt vmcnt(4)" ::: "memory"); // A(t+1)'s 8 landed
      A_WRITE(cur^1);
      asm volatile("s_waitcnt lgkmcnt(0)" ::: "memory");
      BARRIER;                       // WAR + A-write visibility
    }
  }
  #undef A_ISSUE
  #undef A_WRITE
  #undef B_STAGE

  int m0 = mblk*64 + wr*32;
  int n0 = nblk*128 + wc*64;
  #pragma unroll
  for (int i=0;i<2;i++){
    #pragma unroll
    for (int j=0;j<4;j++){
      int n = n0 + j*16 + lr;
      #pragma unroll
      for (int rg=0;rg<4;rg++){
        int m = m0 + i*16 + 4*lg + rg;
        __bf16 hb = (__bf16)acc[i][j][rg];
        gout[(size_t)m*512 + n] = *(u16*)&hb;
      }
    }
  }
}

// LayerNorm pass: out = LN(gout + bo + resid) * g + beta. One wave per row,
// fully vectorized; grid 2048 x 256 (8192 waves = 8192 rows).
__global__ __launch_bounds__(256)
void k_ln(const u16* __restrict__ gout, const float* __restrict__ bo,
          const float* __restrict__ resid, const float* __restrict__ g,
          const float* __restrict__ beta, float* __restrict__ out){
  int gid  = blockIdx.x*256 + threadIdx.x;
  int row  = gid >> 6;
  int lane = gid & 63;
  int c0 = lane*8;
  bf16x8 a = *(const bf16x8*)(gout + (size_t)row*512 + c0);
  float4 r0 = *(const float4*)(resid + (size_t)row*512 + c0);
  float4 r1 = *(const float4*)(resid + (size_t)row*512 + c0 + 4);
  float4 b0 = *(const float4*)(bo + c0);
  float4 b1 = *(const float4*)(bo + c0 + 4);
  float v[8];
  v[0]=(float)a[0]+b0.x+r0.x; v[1]=(float)a[1]+b0.y+r0.y;
  v[2]=(float)a[2]+b0.z+r0.z; v[3]=(float)a[3]+b0.w+r0.w;
  v[4]=(float)a[4]+b1.x+r1.x; v[5]=(float)a[5]+b1.y+r1.y;
  v[6]=(float)a[6]+b1.z+r1.z; v[7]=(float)a[7]+b1.w+r1.w;
  float s1 = 0.f, s2 = 0.f;
  #pragma unroll
  for (int e=0;e<8;e++){ s1 += v[e]; s2 += v[e]*v[e]; }
  #pragma unroll
  for (int mk=1; mk<64; mk<<=1){
    s1 += __shfl_xor(s1, mk);
    s2 += __shfl_xor(s2, mk);
  }
  float mu   = s1 * (1.f/512.f);
  float var  = s2 * (1.f/512.f) - mu*mu;
  float rstd = rsqrtf(var + 1e-5f);
  float4 g0 = *(const float4*)(g + c0);
  float4 g1 = *(const float4*)(g + c0 + 4);
  float4 e0 = *(const float4*)(beta + c0);
  float4 e1 = *(const float4*)(beta + c0 + 4);
  float4 o0, o1;
  o0.x=(v[0]-mu)*rstd*g0.x+e0.x; o0.y=(v[1]-mu)*rstd*g0.y+e0.y;
  o0.z=(v[2]-mu)*rstd*g0.z+e0.z; o0.w=(v[3]-mu)*rstd*g0.w+e0.w;
  o1.x=(v[4]-mu)*rstd*g1.x+e1.x; o1.y=(v[5]-mu)*rstd*g1.y+e1.y;
  o1.z=(v[6]-mu)*rstd*g1.z+e1.z; o1.w=(v[7]-mu)*rstd*g1.w+e1.w;
  *(float4*)(out + (size_t)row*512 + c0)     = o0;
  *(float4*)(out + (size_t)row*512 + c0 + 4) = o1;
}

extern "C" void kernel_launch(void* const* d_in, const int* in_sizes, int n_in,
                              void* d_out, int out_size, void* d_ws, size_t ws_size,
                              hipStream_t stream){
  const float* q   = (const float*)d_in[0];
  const float* k   = (const float*)d_in[1];
  const float* v   = (const float*)d_in[2];
  const float* wq  = (const float*)d_in[3];
  const float* bq  = (const float*)d_in[4];
  const float* wk  = (const float*)d_in[5];
  const float* bk  = (const float*)d_in[6];
  const float* wv  = (const float*)d_in[7];
  const float* bv  = (const float*)d_in[8];
  const float* wo  = (const float*)d_in[9];
  const float* bo  = (const float*)d_in[10];
  const float* lng = (const float*)d_in[11];
  const float* lnb = (const float*)d_in[12];
  float* out = (float*)d_out;
  char* ws = (char*)d_ws;
  u16*   wt    = (u16*)(ws + 0);
  u16*   qb    = (u16*)(ws + 2097152);
  u16*   kb    = (u16*)(ws + 10485760);
  u16*   vt    = (u16*)(ws + 18874368);
  u16*   gout  = (u16*)(ws + 27262976);
  u16*   opart = (u16*)(ws + 35651584);
  float* lpart = (float*)(ws + 52428800);

  k_prep_w<<<dim3(8,8,4), 256, 0, stream>>>(wq, wk, wv, wo, wt);
  k_gemm_qkv<<<1536, 256, 0, stream>>>(q, k, v, wt, bq, bk, bv, qb, kb, vt);
  k_attn<<<512, 512, 0, stream>>>(qb, kb, vt, opart, lpart);
  k_gemm_o<<<512, 256, 0, stream>>>(opart, opart + (size_t)8192*512, lpart,
                                    wt + 3*262144, gout);
  k_ln<<<2048, 256, 0, stream>>>(gout, bo, q, lng, lnb, out);
}